// Round 22
// baseline (53.146 us; speedup 1.0000x reference)
//
#include <hip/hip_runtime.h>
#include <hip/hip_bf16.h>
#include <math.h>

#define EPS 1e-8f

typedef __attribute__((ext_vector_type(2))) unsigned long ulongx2;
typedef __attribute__((ext_vector_type(4))) float floatx4;
typedef unsigned char uchar_t;

#define GPTR(p) ((const __attribute__((address_space(1))) void*)(p))
#define LPTR(p) ((__attribute__((address_space(3))) void*)(p))

__device__ __forceinline__ unsigned int pk4(float a, float b, float c, float d) {
  int v = __builtin_amdgcn_cvt_pk_fp8_f32(a, b, 0, false);
  v = __builtin_amdgcn_cvt_pk_fp8_f32(c, d, v, true);
  return (unsigned int)v;
}

// ---- kA v7: one speaker per block, 512 thr (8 waves). x read via
// global_load_lds DMA into double-buffered LDS (8-row 24KB chunks, 1 ahead,
// vmcnt(3)) -> in-flight bytes decoupled from VGPRs (48KB/CU in flight).
// fbuf rows are WAVE-PRIVATE (wave wv DMAs and reads row wv) -> no barriers
// in the main loop; only the cross-wave fm-gather keeps lgkm+barrier.
// 76.5KB LDS -> 2 blk/CU.
__global__ __launch_bounds__(512, 4) void kA(const float* __restrict__ x,
    uchar_t* __restrict__ xbf8fm, float* __restrict__ sums_f32,
    float* __restrict__ ss, float* __restrict__ rcn,
    float* __restrict__ xx, float* __restrict__ rxn,
    const float* __restrict__ wp) {
  const int n = blockIdx.x;
  const int t = threadIdx.x;           // 0..511
  const int wv = t >> 6, l = t & 63;   // 8 waves
  __shared__ float fbuf[2][8][768];    // 48KB f32 chunk staging (dbuf)
  __shared__ uchar_t xs[16][776];      // 12.1KB padded fp8 group staging
  __shared__ float rqp[64][65];        // 16.3KB row-norm partials
  __shared__ float red8[8];

  const float* xbase = x + (size_t)n * 64 * 768;

  // DMA chunk C_ (rows C_*8..+7): wave wv fills its own row wv (3 x 1KB)
#define DMA(C_) {                                                              \
    const float* src_ = xbase + (size_t)((C_) * 8 + wv) * 768 + l * 4;         \
    __builtin_amdgcn_global_load_lds(GPTR(src_),                               \
        LPTR(&fbuf[(C_) & 1][wv][0]), 16, 0, 0);                               \
    __builtin_amdgcn_global_load_lds(GPTR(src_ + 256),                         \
        LPTR(&fbuf[(C_) & 1][wv][256]), 16, 0, 0);                             \
    __builtin_amdgcn_global_load_lds(GPTR(src_ + 512),                         \
        LPTR(&fbuf[(C_) & 1][wv][512]), 16, 0, 0);                             \
  }

  float4 cs[3] = {{0,0,0,0},{0,0,0,0},{0,0,0,0}};
  DMA(0)

  for (int c = 0; c < 8; ++c) {
    if (c < 7) { DMA(c + 1) asm volatile("s_waitcnt vmcnt(3)" ::: "memory"); }
    else       { asm volatile("s_waitcnt vmcnt(0)" ::: "memory"); }
    __builtin_amdgcn_sched_barrier(0);

    // process own row (wave-private): 3 conflict-free ds_read_b128
    {
      const float* fr = &fbuf[c & 1][wv][0];
      float4 v0 = *(const float4*)(fr + l * 4);
      float4 v1 = *(const float4*)(fr + l * 4 + 256);
      float4 v2 = *(const float4*)(fr + l * 4 + 512);
      const int xr = (c & 1) * 8 + wv;           // xs row within group
      *(unsigned int*)&xs[xr][l * 4]       = pk4(v0.x, v0.y, v0.z, v0.w);
      *(unsigned int*)&xs[xr][l * 4 + 256] = pk4(v1.x, v1.y, v1.z, v1.w);
      *(unsigned int*)&xs[xr][l * 4 + 512] = pk4(v2.x, v2.y, v2.z, v2.w);
      float rq = v0.x*v0.x + v0.y*v0.y + v0.z*v0.z + v0.w*v0.w
               + v1.x*v1.x + v1.y*v1.y + v1.z*v1.z + v1.w*v1.w
               + v2.x*v2.x + v2.y*v2.y + v2.z*v2.z + v2.w*v2.w;
      rqp[c * 8 + wv][l] = rq;
      cs[0].x += v0.x; cs[0].y += v0.y; cs[0].z += v0.z; cs[0].w += v0.w;
      cs[1].x += v1.x; cs[1].y += v1.y; cs[1].z += v1.z; cs[1].w += v1.w;
      cs[2].x += v2.x; cs[2].y += v2.y; cs[2].z += v2.z; cs[2].w += v2.w;
    }

    if (c & 1) {
      // fm-write group g = c>>1: cross-wave xs gather -> 12 x 1KB blobs
      asm volatile("s_waitcnt lgkmcnt(0)" ::: "memory");
      __builtin_amdgcn_s_barrier();
      const int g = n * 4 + (c >> 1);
      {
        const uchar_t* sp = &xs[l & 15][wv * 64 + (l >> 4) * 8];
        uint2 lo = *(const uint2*)sp;
        uint2 hi = *(const uint2*)(sp + 32);
        uint4 outv = {lo.x, lo.y, hi.x, hi.y};
        *(uint4*)(xbf8fm + (size_t)((g * 12 + wv) * 64 + l) * 16) = outv;
      }
      if (wv < 4) {
        const int ks = 8 + wv;
        const uchar_t* sp = &xs[l & 15][ks * 64 + (l >> 4) * 8];
        uint2 lo = *(const uint2*)sp;
        uint2 hi = *(const uint2*)(sp + 32);
        uint4 outv = {lo.x, lo.y, hi.x, hi.y};
        *(uint4*)(xbf8fm + (size_t)((g * 12 + ks) * 64 + l) * 16) = outv;
      }
      __builtin_amdgcn_s_barrier();    // fm reads done before next xs writes
    }
  }

  // ---- row-norm reduce: thread t -> row t>>3, chunk (t&7)*8 of 64 lanes
  {
    const int r = t >> 3;
    const int o = (t & 7) * 8;
    float s = 0.f;
#pragma unroll
    for (int i = 0; i < 8; ++i) s += rqp[r][o + i];
    s += __shfl_xor(s, 1, 64);
    s += __shfl_xor(s, 2, 64);
    s += __shfl_xor(s, 4, 64);
    if ((t & 7) == 0) {
      const int j = n * 64 + r;
      xx[j] = s;
      rxn[j] = 1.0f / fmaxf(sqrtf(s), EPS);
    }
  }

  // ---- csum overlay on fbuf (8 x 768 floats = 24KB)
  float (*csum)[768] = (float (*)[768])&fbuf[0][0][0];
#pragma unroll
  for (int q = 0; q < 3; ++q)
    *(floatx4*)&csum[wv][l * 4 + q * 256] = (floatx4){cs[q].x, cs[q].y, cs[q].z, cs[q].w};
  asm volatile("s_waitcnt lgkmcnt(0)" ::: "memory");
  __builtin_amdgcn_s_barrier();

  // ---- reduce over 8 waves: 768 cols by 512 threads
  float lss = 0.f;
  {
    const int c0 = t;
    float s0 = 0.f;
#pragma unroll
    for (int w = 0; w < 8; ++w) s0 += csum[w][c0];
    sums_f32[(size_t)n * 768 + c0] = s0;
    lss += s0 * s0;
    if (t < 256) {
      const int c1 = 512 + t;
      float s1 = 0.f;
#pragma unroll
      for (int w = 0; w < 8; ++w) s1 += csum[w][c1];
      sums_f32[(size_t)n * 768 + c1] = s1;
      lss += s1 * s1;
    }
  }
  for (int o = 32; o; o >>= 1) lss += __shfl_xor(lss, o, 64);
  if (l == 0) red8[wv] = lss;
  __syncthreads();
  if (t == 0) {
    float vv = 0.f;
#pragma unroll
    for (int w = 0; w < 8; ++w) vv += red8[w];
    ss[n] = vv;
    rcn[n] = (*wp) / fmaxf(sqrtf(vv), 64.f * EPS);   // w / (M * cn)
  }
}

// ---- kA2: sums_f32 -> fp8 fm layout (32 groups x 12 ks x 1KB). Tiny.
__global__ __launch_bounds__(256) void kA2(const float* __restrict__ sums_f32,
    uchar_t* __restrict__ sums8fm) {
  const int g = blockIdx.x;
  const int wv = threadIdx.x >> 6, l = threadIdx.x & 63;
#pragma unroll
  for (int ksi = 0; ksi < 3; ++ksi) {
    const int ks = wv * 3 + ksi;
    const float* sp = sums_f32 + (size_t)(g * 16 + (l & 15)) * 768
                      + ks * 64 + (l >> 4) * 8;
    float4 a0 = *(const float4*)sp;
    float4 a1 = *(const float4*)(sp + 4);
    float4 b0 = *(const float4*)(sp + 32);
    float4 b1 = *(const float4*)(sp + 36);
    uint4 outv = { pk4(a0.x, a0.y, a0.z, a0.w), pk4(a1.x, a1.y, a1.z, a1.w),
                   pk4(b0.x, b0.y, b0.z, b0.w), pk4(b1.x, b1.y, b1.z, b1.w) };
    *(uint4*)(sums8fm + (size_t)((g * 12 + ks) * 64 + l) * 16) = outv;
  }
}

// ---- kC: fp8 GEMM, 256n x 256j tile, 256 blocks (1/CU), 8 waves.
// fm-layout operands -> gload_lds reads contiguous 1KB blobs (L2-linear).
// 12 K64-steps, 4 x 32KB buffers, counted vmcnt. colsum via plain stores
// into colsum_part[4][32768]; diagonal sx extraction (exact cancellation).
__global__ __launch_bounds__(512, 2) void kC(const uchar_t* __restrict__ xbf8fm,
    const uchar_t* __restrict__ sums8fm, const float* __restrict__ rcn,
    const float* __restrict__ rxn, float* __restrict__ colsum_part,
    float* __restrict__ sdiag_dot, const float* __restrict__ bp) {
  __shared__ uchar_t lds[4][32768];    // [A blobs 0..15 | B blobs 0..15] x 1KB
  const int b = blockIdx.x;
  const int xcd = b & 7;
  const int inner = b >> 3;
  const int nt = inner & 1;
  const int jt = xcd + ((inner >> 1) << 3);
  const int n0 = nt * 256, j0 = jt * 256;
  const int t = threadIdx.x, wv = t >> 6, l = t & 63;
  const int wm = wv >> 2, wj = wv & 3;
  const int gA0 = n0 / 16, gB0 = j0 / 16;

#define STAGE(KS_, BUF_) {                                                     \
    const int fb0_ = wv * 2, fb1_ = wv * 2 + 1;                                \
    __builtin_amdgcn_global_load_lds(                                          \
        GPTR(sums8fm + (size_t)(((gA0 + fb0_) * 12 + (KS_)) * 64 + l) * 16),   \
        LPTR(&lds[BUF_][fb0_ * 1024]), 16, 0, 0);                              \
    __builtin_amdgcn_global_load_lds(                                          \
        GPTR(sums8fm + (size_t)(((gA0 + fb1_) * 12 + (KS_)) * 64 + l) * 16),   \
        LPTR(&lds[BUF_][fb1_ * 1024]), 16, 0, 0);                              \
    __builtin_amdgcn_global_load_lds(                                          \
        GPTR(xbf8fm + (size_t)(((gB0 + fb0_) * 12 + (KS_)) * 64 + l) * 16),    \
        LPTR(&lds[BUF_][16384 + fb0_ * 1024]), 16, 0, 0);                      \
    __builtin_amdgcn_global_load_lds(                                          \
        GPTR(xbf8fm + (size_t)(((gB0 + fb1_) * 12 + (KS_)) * 64 + l) * 16),    \
        LPTR(&lds[BUF_][16384 + fb1_ * 1024]), 16, 0, 0);                      \
  }

  floatx4 acc[8][4];
#pragma unroll
  for (int mi = 0; mi < 8; ++mi)
#pragma unroll
    for (int ni = 0; ni < 4; ++ni) acc[mi][ni] = (floatx4){0.f, 0.f, 0.f, 0.f};

  STAGE(0, 0)
  STAGE(1, 1)
  STAGE(2, 2)                          // 12 loads/thread outstanding

  for (int kb = 0; kb < 12; ++kb) {
    if (kb < 10)       { asm volatile("s_waitcnt vmcnt(8)" ::: "memory"); }
    else if (kb == 10) { asm volatile("s_waitcnt vmcnt(4)" ::: "memory"); }
    else               { asm volatile("s_waitcnt vmcnt(0)" ::: "memory"); }
    __builtin_amdgcn_s_barrier();
    __builtin_amdgcn_sched_barrier(0);   // keep ds_reads below the barrier
    const int cb = kb & 3, sb = (kb + 3) & 3;

    ulongx2 af[8], bf[4];
#pragma unroll
    for (int ni = 0; ni < 4; ++ni)
      bf[ni] = *(const ulongx2*)&lds[cb][16384 + (wj * 4 + ni) * 1024 + l * 16];
#pragma unroll
    for (int mi = 0; mi < 8; ++mi)
      af[mi] = *(const ulongx2*)&lds[cb][(wm * 8 + mi) * 1024 + l * 16];
    if (kb + 3 < 12) STAGE(kb + 3, sb)
    __builtin_amdgcn_s_setprio(1);
#pragma unroll
    for (int mi = 0; mi < 8; ++mi)
#pragma unroll
      for (int ni = 0; ni < 4; ++ni) {
        acc[mi][ni] = __builtin_amdgcn_mfma_f32_16x16x32_fp8_fp8(
            (long)af[mi].x, (long)bf[ni].x, acc[mi][ni], 0, 0, 0);
        acc[mi][ni] = __builtin_amdgcn_mfma_f32_16x16x32_fp8_fp8(
            (long)af[mi].y, (long)bf[ni].y, acc[mi][ni], 0, 0, 0);
      }
    __builtin_amdgcn_s_setprio(0);
  }

  // ---- epilogue: S = acc * rcn[n] * rxn[j] + b ; partial colsum; diag sx.
  const float bb = *bp;
  float rxv[4], p[4] = {0.f, 0.f, 0.f, 0.f};
#pragma unroll
  for (int ni = 0; ni < 4; ++ni)
    rxv[ni] = rxn[j0 + wj * 64 + ni * 16 + (l & 15)];
  const bool diagblk = (nt == (jt >> 6));

#pragma unroll
  for (int mi = 0; mi < 8; ++mi) {
    float4 rr = *(const float4*)&rcn[n0 + wm * 128 + mi * 16 + ((l >> 4) << 2)];
    const float rc[4] = {rr.x, rr.y, rr.z, rr.w};
#pragma unroll
    for (int ni = 0; ni < 4; ++ni) {
      floatx4 a = acc[mi][ni];
#pragma unroll
      for (int q = 0; q < 4; ++q)
        p[ni] += __expf(a[q] * rc[q] * rxv[ni] + bb);
      if (diagblk) {
        const int jg = j0 + wj * 64 + ni * 16 + (l & 15);
#pragma unroll
        for (int q = 0; q < 4; ++q) {
          const int mg = n0 + wm * 128 + mi * 16 + ((l >> 4) << 2) + q;
          if (mg == (jg >> 6)) sdiag_dot[jg] = a[q];
        }
      }
    }
  }
#pragma unroll
  for (int ni = 0; ni < 4; ++ni) {
    p[ni] += __shfl_xor(p[ni], 16, 64);
    p[ni] += __shfl_xor(p[ni], 32, 64);
  }
  if (l < 16) {
    const int slot = nt * 2 + wm;
#pragma unroll
    for (int ni = 0; ni < 4; ++ni)
      colsum_part[(size_t)slot * 32768 + j0 + wj * 64 + ni * 16 + l] = p[ni];
  }
}

// ---- kD: per-sample loss from 4 colsum partials + diagonal dot -> block
// partials (no atomics, no pre-zero needed).
__global__ __launch_bounds__(256) void kD(const float* __restrict__ colsum_part,
    const float* __restrict__ sdiag_dot, const float* __restrict__ xx,
    const float* __restrict__ ss, const float* __restrict__ rcn,
    const float* __restrict__ wp, const float* __restrict__ bp,
    float* __restrict__ partial) {
  const int j = blockIdx.x * 256 + threadIdx.x;
  const int i = j >> 6;
  const float ww = *wp, bb = *bp;
  const float sx = sdiag_dot[j];
  const float xxv = xx[j];
  const float xn = fmaxf(sqrtf(xxv), EPS);
  const float rx = 1.0f / xn;
  const float sd = sx * rcn[i] * rx + bb;                         // S_diag
  const float exn = sqrtf(fmaxf(ss[i] - 2.f * sx + xxv, 0.f)) * (1.f / 63.f);
  const float edot = (sx - xxv) * (1.f / 63.f);
  const float sm = ww * edot / (fmaxf(exn, EPS) * xn) + bb;       // S_same
  const float cssum = colsum_part[j] + colsum_part[32768 + j]
                    + colsum_part[65536 + j] + colsum_part[98304 + j];
  const float tot = cssum - __expf(sd) + __expf(sm);
  float L = -sm + logf(fmaxf(tot, 1e-30f));
  for (int o = 32; o; o >>= 1) L += __shfl_xor(L, o, 64);
  __shared__ float red[4];
  if ((threadIdx.x & 63) == 0) red[threadIdx.x >> 6] = L;
  __syncthreads();
  if (threadIdx.x == 0)
    partial[blockIdx.x] = red[0] + red[1] + red[2] + red[3];
}

// ---- kE: reduce 128 block partials -> out (plain store, no atomic).
__global__ __launch_bounds__(128) void kE(const float* __restrict__ partial,
    float* __restrict__ out) {
  const int t = threadIdx.x;
  float v = partial[t];
  for (int o = 32; o; o >>= 1) v += __shfl_xor(v, o, 64);
  __shared__ float r2[2];
  if ((t & 63) == 0) r2[t >> 6] = v;
  __syncthreads();
  if (t == 0) out[0] = r2[0] + r2[1];
}

extern "C" void kernel_launch(void* const* d_in, const int* in_sizes, int n_in,
                              void* d_out, int out_size, void* d_ws, size_t ws_size,
                              hipStream_t stream) {
  const float* x  = (const float*)d_in[0];
  const float* wp = (const float*)d_in[1];
  const float* bp = (const float*)d_in[2];
  float* out = (float*)d_out;

  // ws layout (float offsets):
  float* fws = (float*)d_ws;
  float* ss          = fws;              // 512
  float* rcn         = fws + 512;        // 512
  float* xx          = fws + 1024;       // 32768
  float* rxn         = fws + 33792;      // 32768
  float* colsum_part = fws + 66560;      // 131072 (4 x 32768)
  float* sdiag_dot   = fws + 197632;     // 32768
  float* partial     = fws + 230400;     // 128
  float* sums_f32    = fws + 230528;     // 393216
  uchar_t* sums8fm   = (uchar_t*)(fws + 623744);  // 393216 bytes
  uchar_t* xbf8fm    = (uchar_t*)(fws + 722048);  // 25165824 bytes
  // total ~= 28.0 MiB; NO memsets needed (all buffers fully overwritten)

  kA<<<512, 512, 0, stream>>>(x, xbf8fm, sums_f32, ss, rcn, xx, rxn, wp);
  kA2<<<32, 256, 0, stream>>>(sums_f32, sums8fm);
  kC<<<256, 512, 0, stream>>>(xbf8fm, sums8fm, rcn, rxn, colsum_part, sdiag_dot, bp);
  kD<<<128, 256, 0, stream>>>(colsum_part, sdiag_dot, xx, ss, rcn, wp, bp, partial);
  kE<<<1, 128, 0, stream>>>(partial, out);
}

// Round 23
// 51.723 us; speedup vs baseline: 1.0275x; 1.0275x over previous
//
#include <hip/hip_runtime.h>
#include <hip/hip_bf16.h>
#include <math.h>

#define EPS 1e-8f

typedef __attribute__((ext_vector_type(2))) unsigned long ulongx2;
typedef __attribute__((ext_vector_type(4))) float floatx4;
typedef unsigned char uchar_t;

#define GPTR(p) ((const __attribute__((address_space(1))) void*)(p))
#define LPTR(p) ((__attribute__((address_space(3))) void*)(p))

__device__ __forceinline__ unsigned int pk4(float a, float b, float c, float d) {
  int v = __builtin_amdgcn_cvt_pk_fp8_f32(a, b, 0, false);
  v = __builtin_amdgcn_cvt_pk_fp8_f32(c, d, v, true);
  return (unsigned int)v;
}

// ---- kA (R21-best): one speaker per block, 512 thr. Batched loads, no
// per-row shfl chains (rqp LDS), col sums via LDS overlay. 66.4KB LDS.
__global__ __launch_bounds__(512, 4) void kA(const float* __restrict__ x,
    uchar_t* __restrict__ xbf8fm, float* __restrict__ sums_f32,
    float* __restrict__ ss, float* __restrict__ rcn,
    float* __restrict__ xx, float* __restrict__ rxn,
    const float* __restrict__ wp) {
  const int n = blockIdx.x;
  const int t = threadIdx.x;           // 0..511
  const int wv = t >> 6, l = t & 63;   // 8 waves
  __shared__ uchar_t xs[64][776];      // 49.7KB padded fp8 staging
  __shared__ float rqp[64][65];        // 16.6KB row-norm partials
  __shared__ float red8[8];

  float4 cs[3] = {{0,0,0,0},{0,0,0,0},{0,0,0,0}};
  for (int c = 0; c < 2; ++c) {
    float4 v[4][3];
#pragma unroll
    for (int rr = 0; rr < 4; ++rr) {
      const int r = wv * 8 + c * 4 + rr;
      const float* rp = x + ((size_t)n * 64 + r) * 768 + l * 4;
#pragma unroll
      for (int q = 0; q < 3; ++q) v[rr][q] = *(const float4*)(rp + q * 256);
    }
#pragma unroll
    for (int rr = 0; rr < 4; ++rr) {
      const int r = wv * 8 + c * 4 + rr;
      float rq = 0.f;
#pragma unroll
      for (int q = 0; q < 3; ++q) {
        const float4 u = v[rr][q];
        *(unsigned int*)&xs[r][l * 4 + q * 256] = pk4(u.x, u.y, u.z, u.w);
        rq += u.x*u.x + u.y*u.y + u.z*u.z + u.w*u.w;
        cs[q].x += u.x; cs[q].y += u.y; cs[q].z += u.z; cs[q].w += u.w;
      }
      rqp[r][l] = rq;
    }
  }
  __syncthreads();

  // fm-layout fp8 write: wave pair (2gg,2gg+1) handles group gg (6+6 ks)
  {
    const int gg = wv >> 1;
    const int half = wv & 1;
    const int g = n * 4 + gg;
#pragma unroll
    for (int ksi = 0; ksi < 6; ++ksi) {
      const int ks = half * 6 + ksi;
      const uchar_t* sp = &xs[gg * 16 + (l & 15)][ks * 64 + (l >> 4) * 8];
      uint2 lo = *(const uint2*)sp;
      uint2 hi = *(const uint2*)(sp + 32);
      uint4 outv = {lo.x, lo.y, hi.x, hi.y};
      *(uint4*)(xbf8fm + (size_t)((g * 12 + ks) * 64 + l) * 16) = outv;
    }
  }

  // row-norm reduce
  {
    const int r = t >> 3;
    const int o = (t & 7) * 8;
    float s = 0.f;
#pragma unroll
    for (int i = 0; i < 8; ++i) s += rqp[r][o + i];
    s += __shfl_xor(s, 1, 64);
    s += __shfl_xor(s, 2, 64);
    s += __shfl_xor(s, 4, 64);
    if ((t & 7) == 0) {
      const int j = n * 64 + r;
      xx[j] = s;
      rxn[j] = 1.0f / fmaxf(sqrtf(s), EPS);
    }
  }
  __syncthreads();

  float (*csum)[768] = (float (*)[768])&xs[0][0];
#pragma unroll
  for (int q = 0; q < 3; ++q)
    *(floatx4*)&csum[wv][l * 4 + q * 256] = (floatx4){cs[q].x, cs[q].y, cs[q].z, cs[q].w};
  __syncthreads();

  float lss = 0.f;
  {
    const int c0 = t;
    float s0 = 0.f;
#pragma unroll
    for (int w = 0; w < 8; ++w) s0 += csum[w][c0];
    sums_f32[(size_t)n * 768 + c0] = s0;
    lss += s0 * s0;
    if (t < 256) {
      const int c1 = 512 + t;
      float s1 = 0.f;
#pragma unroll
      for (int w = 0; w < 8; ++w) s1 += csum[w][c1];
      sums_f32[(size_t)n * 768 + c1] = s1;
      lss += s1 * s1;
    }
  }
  for (int o = 32; o; o >>= 1) lss += __shfl_xor(lss, o, 64);
  if (l == 0) red8[wv] = lss;
  __syncthreads();
  if (t == 0) {
    float vv = 0.f;
#pragma unroll
    for (int w = 0; w < 8; ++w) vv += red8[w];
    ss[n] = vv;
    rcn[n] = (*wp) / fmaxf(sqrtf(vv), 64.f * EPS);   // w / (M * cn)
  }
}

// ---- kA2: sums_f32 -> fp8 fm layout. Tiny.
__global__ __launch_bounds__(256) void kA2(const float* __restrict__ sums_f32,
    uchar_t* __restrict__ sums8fm) {
  const int g = blockIdx.x;
  const int wv = threadIdx.x >> 6, l = threadIdx.x & 63;
#pragma unroll
  for (int ksi = 0; ksi < 3; ++ksi) {
    const int ks = wv * 3 + ksi;
    const float* sp = sums_f32 + (size_t)(g * 16 + (l & 15)) * 768
                      + ks * 64 + (l >> 4) * 8;
    float4 a0 = *(const float4*)sp;
    float4 a1 = *(const float4*)(sp + 4);
    float4 b0 = *(const float4*)(sp + 32);
    float4 b1 = *(const float4*)(sp + 36);
    uint4 outv = { pk4(a0.x, a0.y, a0.z, a0.w), pk4(a1.x, a1.y, a1.z, a1.w),
                   pk4(b0.x, b0.y, b0.z, b0.w), pk4(b1.x, b1.y, b1.z, b1.w) };
    *(uint4*)(sums8fm + (size_t)((g * 12 + ks) * 64 + l) * 16) = outv;
  }
}

// ---- kC v8: fp8 GEMM, tile 128n x 256j, 512 blocks (2/CU: cross-block
// stall covering), 8 waves of 64n x 64j. 2 x 24KB buffers, 2-deep vmcnt(3),
// barrier-after-reads before same-buffer stage. fm-blob machinery unchanged.
__global__ __launch_bounds__(512) void kC(const uchar_t* __restrict__ xbf8fm,
    const uchar_t* __restrict__ sums8fm, const float* __restrict__ rcn,
    const float* __restrict__ rxn, float* __restrict__ colsum_part,
    float* __restrict__ sdiag_dot, const float* __restrict__ bp) {
  __shared__ uchar_t lds[2][24576];    // [A blobs 0..7 | B blobs 0..15] x 1KB
  const int b = blockIdx.x;
  const int xcd = b & 7;
  const int inner = b >> 3;            // 0..63
  const int nt = inner & 3;            // 4 n-slices of 128 share jt's B on XCD
  const int jt = xcd + ((inner >> 2) << 3);   // 0..127
  const int n0 = nt * 128, j0 = jt * 256;
  const int t = threadIdx.x, wv = t >> 6, l = t & 63;
  const int wm = wv >> 2, wj = wv & 3; // 2(m) x 4(j); wave = 64n x 64j
  const int gA0 = n0 >> 4, gB0 = j0 >> 4;

// stage K64-step KS_ into buffer BUF_: wave wv stages blobs 3wv..3wv+2
#define STAGE(KS_, BUF_) {                                                     \
    _Pragma("unroll")                                                          \
    for (int i_ = 0; i_ < 3; ++i_) {                                           \
      const int bl_ = wv * 3 + i_;                                             \
      if (bl_ < 8) {                                                           \
        __builtin_amdgcn_global_load_lds(                                      \
            GPTR(sums8fm + (size_t)(((gA0 + bl_) * 12 + (KS_)) * 64 + l) * 16),\
            LPTR(&lds[BUF_][bl_ * 1024 + l * 16]), 16, 0, 0);                  \
      } else {                                                                 \
        __builtin_amdgcn_global_load_lds(                                      \
            GPTR(xbf8fm + (size_t)(((gB0 + bl_ - 8) * 12 + (KS_)) * 64 + l) * 16), \
            LPTR(&lds[BUF_][bl_ * 1024 + l * 16]), 16, 0, 0);                  \
      }                                                                        \
    }                                                                          \
  }

  floatx4 acc[4][4];
#pragma unroll
  for (int mi = 0; mi < 4; ++mi)
#pragma unroll
    for (int ni = 0; ni < 4; ++ni) acc[mi][ni] = (floatx4){0.f, 0.f, 0.f, 0.f};

  STAGE(0, 0)
  STAGE(1, 1)                          // 6 loads/thread outstanding

  for (int kb = 0; kb < 12; ++kb) {
    if (kb < 11) { asm volatile("s_waitcnt vmcnt(3)" ::: "memory"); }
    else         { asm volatile("s_waitcnt vmcnt(0)" ::: "memory"); }
    __builtin_amdgcn_s_barrier();      // buffer kb&1 fully staged
    __builtin_amdgcn_sched_barrier(0);
    const int cb = kb & 1;

    ulongx2 af[4], bf[4];
#pragma unroll
    for (int mi = 0; mi < 4; ++mi)
      af[mi] = *(const ulongx2*)&lds[cb][(wm * 4 + mi) * 1024 + l * 16];
#pragma unroll
    for (int ni = 0; ni < 4; ++ni)
      bf[ni] = *(const ulongx2*)&lds[cb][8192 + (wj * 4 + ni) * 1024 + l * 16];
    asm volatile("s_waitcnt lgkmcnt(0)" ::: "memory");
    __builtin_amdgcn_s_barrier();      // all waves' reads of cb done
    __builtin_amdgcn_sched_barrier(0);
    if (kb + 2 < 12) STAGE(kb + 2, cb) // safe: cb just fully consumed
    __builtin_amdgcn_s_setprio(1);
#pragma unroll
    for (int mi = 0; mi < 4; ++mi)
#pragma unroll
      for (int ni = 0; ni < 4; ++ni) {
        acc[mi][ni] = __builtin_amdgcn_mfma_f32_16x16x32_fp8_fp8(
            (long)af[mi].x, (long)bf[ni].x, acc[mi][ni], 0, 0, 0);
        acc[mi][ni] = __builtin_amdgcn_mfma_f32_16x16x32_fp8_fp8(
            (long)af[mi].y, (long)bf[ni].y, acc[mi][ni], 0, 0, 0);
      }
    __builtin_amdgcn_s_setprio(0);
  }

  // ---- epilogue: S = acc * rcn[n] * rxn[j] + b ; partial colsum; diag sx.
  const float bb = *bp;
  float rxv[4], p[4] = {0.f, 0.f, 0.f, 0.f};
#pragma unroll
  for (int ni = 0; ni < 4; ++ni)
    rxv[ni] = rxn[j0 + wj * 64 + ni * 16 + (l & 15)];
  const bool diagblk = (nt == (jt >> 5));

#pragma unroll
  for (int mi = 0; mi < 4; ++mi) {
    float4 rr = *(const float4*)&rcn[n0 + wm * 64 + mi * 16 + ((l >> 4) << 2)];
    const float rc[4] = {rr.x, rr.y, rr.z, rr.w};
#pragma unroll
    for (int ni = 0; ni < 4; ++ni) {
      floatx4 a = acc[mi][ni];
#pragma unroll
      for (int q = 0; q < 4; ++q)
        p[ni] += __expf(a[q] * rc[q] * rxv[ni] + bb);
      if (diagblk) {
        const int jg = j0 + wj * 64 + ni * 16 + (l & 15);
#pragma unroll
        for (int q = 0; q < 4; ++q) {
          const int mg = n0 + wm * 64 + mi * 16 + ((l >> 4) << 2) + q;
          if (mg == (jg >> 6)) sdiag_dot[jg] = a[q];
        }
      }
    }
  }
#pragma unroll
  for (int ni = 0; ni < 4; ++ni) {
    p[ni] += __shfl_xor(p[ni], 16, 64);
    p[ni] += __shfl_xor(p[ni], 32, 64);
  }
  if (l < 16) {
    const int slot = nt * 2 + wm;      // 8 slots, unique writer per (slot,j)
#pragma unroll
    for (int ni = 0; ni < 4; ++ni)
      colsum_part[(size_t)slot * 32768 + j0 + wj * 64 + ni * 16 + l] = p[ni];
  }
}

// ---- kD: per-sample loss from 8 colsum partials + diagonal dot ----------
__global__ __launch_bounds__(256) void kD(const float* __restrict__ colsum_part,
    const float* __restrict__ sdiag_dot, const float* __restrict__ xx,
    const float* __restrict__ ss, const float* __restrict__ rcn,
    const float* __restrict__ wp, const float* __restrict__ bp,
    float* __restrict__ partial) {
  const int j = blockIdx.x * 256 + threadIdx.x;
  const int i = j >> 6;
  const float ww = *wp, bb = *bp;
  const float sx = sdiag_dot[j];
  const float xxv = xx[j];
  const float xn = fmaxf(sqrtf(xxv), EPS);
  const float rx = 1.0f / xn;
  const float sd = sx * rcn[i] * rx + bb;                         // S_diag
  const float exn = sqrtf(fmaxf(ss[i] - 2.f * sx + xxv, 0.f)) * (1.f / 63.f);
  const float edot = (sx - xxv) * (1.f / 63.f);
  const float sm = ww * edot / (fmaxf(exn, EPS) * xn) + bb;       // S_same
  float cssum = 0.f;
#pragma unroll
  for (int s = 0; s < 8; ++s) cssum += colsum_part[(size_t)s * 32768 + j];
  const float tot = cssum - __expf(sd) + __expf(sm);
  float L = -sm + logf(fmaxf(tot, 1e-30f));
  for (int o = 32; o; o >>= 1) L += __shfl_xor(L, o, 64);
  __shared__ float red[4];
  if ((threadIdx.x & 63) == 0) red[threadIdx.x >> 6] = L;
  __syncthreads();
  if (threadIdx.x == 0)
    partial[blockIdx.x] = red[0] + red[1] + red[2] + red[3];
}

// ---- kE: reduce 128 block partials -> out.
__global__ __launch_bounds__(128) void kE(const float* __restrict__ partial,
    float* __restrict__ out) {
  const int t = threadIdx.x;
  float v = partial[t];
  for (int o = 32; o; o >>= 1) v += __shfl_xor(v, o, 64);
  __shared__ float r2[2];
  if ((t & 63) == 0) r2[t >> 6] = v;
  __syncthreads();
  if (t == 0) out[0] = r2[0] + r2[1];
}

extern "C" void kernel_launch(void* const* d_in, const int* in_sizes, int n_in,
                              void* d_out, int out_size, void* d_ws, size_t ws_size,
                              hipStream_t stream) {
  const float* x  = (const float*)d_in[0];
  const float* wp = (const float*)d_in[1];
  const float* bp = (const float*)d_in[2];
  float* out = (float*)d_out;

  // ws layout (float offsets):
  float* fws = (float*)d_ws;
  float* ss          = fws;              // 512
  float* rcn         = fws + 512;        // 512
  float* xx          = fws + 1024;       // 32768
  float* rxn         = fws + 33792;      // 32768
  float* colsum_part = fws + 66560;      // 262144 (8 x 32768)
  float* sdiag_dot   = fws + 328704;     // 32768
  float* partial     = fws + 361472;     // 128
  float* sums_f32    = fws + 361600;     // 393216
  uchar_t* sums8fm   = (uchar_t*)(fws + 754816);  // 393216 bytes
  uchar_t* xbf8fm    = (uchar_t*)(fws + 853120);  // 25165824 bytes
  // total ~= 28.6 MiB; NO memsets (all buffers fully overwritten)

  kA<<<512, 512, 0, stream>>>(x, xbf8fm, sums_f32, ss, rcn, xx, rxn, wp);
  kA2<<<32, 256, 0, stream>>>(sums_f32, sums8fm);
  kC<<<512, 512, 0, stream>>>(xbf8fm, sums8fm, rcn, rxn, colsum_part, sdiag_dot, bp);
  kD<<<128, 256, 0, stream>>>(colsum_part, sdiag_dot, xx, ss, rcn, wp, bp, partial);
  kE<<<1, 128, 0, stream>>>(partial, out);
}